// Round 6
// baseline (9094.601 us; speedup 1.0000x reference)
//
#include <hip/hip_runtime.h>

#define TT   1024
#define BB   64
#define DIN  256
#define HH   512
#define DOUT 256

#define NWG_L0  64
#define NWG_L1  128
#define NWG_OUT 8
#define NWG_TOT 200
#define NBARRIERS (1 + (TT + 2))

typedef short bf16x8 __attribute__((ext_vector_type(8)));
typedef float f32x4  __attribute__((ext_vector_type(4)));

// frag-ordered bf16 tensors: index f = ((ks*4 + ct)*64 + lane), element e
// value = M[k = ks*32 + (lane>>4)*8 + e][col = ct*16 + (lane&15)]
__device__ bf16x8 g_xf[TT * 2048];     // x packed: 8 ks x 4 ct x 64 lanes per t (32 MB)
__device__ bf16x8 g_h1f[2][4096];      // h1 ring: 16 ks x 4 ct x 64
__device__ bf16x8 g_h2f[2][4096];      // h2 ring

// replay-safe epoch barrier state (zero-initialized at module load)
__device__ unsigned g_arrive[NWG_TOT * 16];
__device__ unsigned g_release;
__device__ unsigned g_epoch_base;

__device__ __forceinline__ void gridbar(unsigned e, int wg, int tid) {
    __syncthreads();
    if (tid == 0)
        __hip_atomic_store(&g_arrive[wg * 16], e, __ATOMIC_RELEASE, __HIP_MEMORY_SCOPE_AGENT);
    if (wg == 0) {
        for (int s = tid; s < NWG_TOT; s += 256) {
            while (__hip_atomic_load(&g_arrive[s * 16], __ATOMIC_RELAXED,
                                     __HIP_MEMORY_SCOPE_AGENT) != e) {}
        }
        __builtin_amdgcn_fence(__ATOMIC_ACQUIRE, "agent");
        __syncthreads();
        if (tid == 0)
            __hip_atomic_store(&g_release, e, __ATOMIC_RELEASE, __HIP_MEMORY_SCOPE_AGENT);
    } else {
        if (tid == 0) {
            while (__hip_atomic_load(&g_release, __ATOMIC_RELAXED,
                                     __HIP_MEMORY_SCOPE_AGENT) != e) {}
            __builtin_amdgcn_fence(__ATOMIC_ACQUIRE, "agent");
        }
        __syncthreads();
    }
}

__device__ __forceinline__ float sigf(float v) { return 1.f / (1.f + __expf(-v)); }
__device__ __forceinline__ float tanh_fast(float v) { return 2.f / (1.f + __expf(-2.f * v)) - 1.f; }

__device__ __forceinline__ short f2bf(float f) {   // RNE float->bf16 bits
    unsigned u = __builtin_bit_cast(unsigned, f);
    unsigned r = (u + 0x7FFFu + ((u >> 16) & 1u)) >> 16;
    return (short)r;
}

__device__ __forceinline__ bf16x8 pack8(float4 v0, float4 v1) {
    bf16x8 r;
    r[0] = f2bf(v0.x); r[1] = f2bf(v0.y); r[2] = f2bf(v0.z); r[3] = f2bf(v0.w);
    r[4] = f2bf(v1.x); r[5] = f2bf(v1.y); r[6] = f2bf(v1.z); r[7] = f2bf(v1.w);
    return r;
}

// ---------------- pre-pass: pack x (fp32 [T][B][DIN]) into frag-ordered bf16
extern "C" __global__ void __launch_bounds__(256)
pack_x(const float* __restrict__ x) {
    const int t = blockIdx.x, tid = threadIdx.x;
    const float* xt = x + (size_t)t * BB * DIN;
    bf16x8* dst = g_xf + (size_t)t * 2048;
    #pragma unroll
    for (int u = 0; u < 8; ++u) {
        const int f = u * 256 + tid;
        const int lane_ = f & 63, ctks = f >> 6;
        const int ct = ctks & 3, ks = ctks >> 2;
        const int b  = ct * 16 + (lane_ & 15);
        const int kb = ks * 32 + (lane_ >> 4) * 8;
        const float4* s = (const float4*)(xt + b * DIN + kb);
        dst[f] = pack8(s[0], s[1]);
    }
}

// ---------------- LSTM layer: wave owns 4 hidden units x NCT batch-quadrants
// L=0: in=[x_t ; h1_{t-1}] K=768, NCT=2 ; L=1: in=[h1_t ; h2_{t-1}] K=1024, NCT=1
template<int L, int NCT>
__device__ void run_layer(int lwg, int wg, int tid,
                          const float* __restrict__ wih, const float* __restrict__ whh,
                          const float* __restrict__ bih, const float* __restrict__ bhh,
                          float* __restrict__ out, unsigned ep)
{
    constexpr int KINX = (L == 0) ? DIN : HH;
    constexpr int NKSX = KINX / 32;          // x-part frags (8 or 16)
    constexpr int NKSB = HH / 32;            // 16 h-part frags
    constexpr int NKS  = NKSX + NKSB;
    constexpr int NCG  = 4 / NCT;            // ct-groups per WG
    constexpr int NBB  = NKS * NCT;          // B-frags per wave (48 or 32)

    const int lane = tid & 63, lo = lane & 15, hi = lane >> 4;
    const int w      = tid >> 6;
    const int ug     = w / NCG;              // unit-group within WG [0,NCT)
    const int ctbase = (w % NCG) * NCT;
    const int wv     = lwg * NCT + ug;       // global unit-group [0,128)
    const int jbase  = wv * 4;
    const int grow   = (lo & 3) * HH + jbase + (lo >> 2);  // gate-major A-row

    // --- this wave's weights as bf16 A-fragments in registers (loaded once)
    bf16x8 aF[NKS];
    #pragma unroll
    for (int ks = 0; ks < NKS; ++ks) {
        const float* wr;
        if (ks * 32 < KINX) wr = wih + (size_t)grow * KINX + ks * 32 + hi * 8;
        else                wr = whh + (size_t)grow * HH + (ks - NKSX) * 32 + hi * 8;
        const float4* p = (const float4*)wr;
        aF[ks] = pack8(p[0], p[1]);
    }

    f32x4 biasv;
    #pragma unroll
    for (int r = 0; r < 4; ++r)
        biasv[r] = bih[r * HH + jbase + hi] + bhh[r * HH + jbase + hi];

    // h-ring write slot for unit j = jbase+hi
    const int wksp = wv >> 3, wkhi = (wv >> 1) & 3, wel = (wv & 1) * 4 + hi;

    float cst[NCT];
    #pragma unroll
    for (int c = 0; c < NCT; ++c) cst[c] = 0.f;

    for (int s = 0; s <= TT + 1; ++s) {
        const int t = (L == 0) ? s : s - 1;
        if (t >= 0 && t < TT) {
            const bf16x8* srcA = (L == 0) ? (g_xf + (size_t)t * 2048) : g_h1f[t & 1];
            const bf16x8* srcB = (L == 0) ? g_h1f[(t + 1) & 1] : g_h2f[(t + 1) & 1];

            // ---- issue the ENTIRE B batch, pin it, then consume
            bf16x8 bb[NBB];
            #pragma unroll
            for (int ks = 0; ks < NKSX; ++ks)
                #pragma unroll
                for (int c = 0; c < NCT; ++c)
                    bb[ks * NCT + c] = srcA[(ks * 4 + ctbase + c) * 64 + lane];
            #pragma unroll
            for (int ks = 0; ks < NKSB; ++ks)
                #pragma unroll
                for (int c = 0; c < NCT; ++c)
                    bb[(NKSX + ks) * NCT + c] = srcB[(ks * 4 + ctbase + c) * 64 + lane];
            __builtin_amdgcn_sched_barrier(0);   // loads stay above: one latency exposure

            f32x4 acc[NCT];
            #pragma unroll
            for (int c = 0; c < NCT; ++c) acc[c] = biasv;
            #pragma unroll
            for (int ks = 0; ks < NKS; ++ks)
                #pragma unroll
                for (int c = 0; c < NCT; ++c)
                    acc[c] = __builtin_amdgcn_mfma_f32_16x16x32_bf16(
                        aF[ks], bb[ks * NCT + c], acc[c], 0, 0, 0);

            // lane (hi,lo): gates i,f,g,o for unit j=jbase+hi, batch b=ct*16+lo
            short* ringW = (short*)((L == 0) ? g_h1f[t & 1] : g_h2f[t & 1]);
            #pragma unroll
            for (int c = 0; c < NCT; ++c) {
                const int ct = ctbase + c;
                const float gi = acc[c][0], gf = acc[c][1];
                const float gg = acc[c][2], go = acc[c][3];
                const float cn_ = sigf(gf) * cst[c] + sigf(gi) * tanh_fast(gg);
                const float hv  = sigf(go) * tanh_fast(cn_);
                cst[c] = cn_;
                ringW[(((wksp * 4 + ct) * 64) + wkhi * 16 + lo) * 8 + wel] = f2bf(hv);
                if (t == TT - 1) {
                    const int j = jbase + hi, b = ct * 16 + lo;
                    const size_t base = (size_t)TT * BB * DOUT;
                    out[base + (size_t)L * BB * HH + (size_t)b * HH + j] = hv;
                    out[base + (size_t)2 * BB * HH + (size_t)L * BB * HH + (size_t)b * HH + j] = cn_;
                }
            }
        }
        gridbar(++ep, wg, tid);
    }
}

// ---------------- output projection: wave owns 16 output dims x 2 quadrants
__device__ void run_out(int lwg, int wg, int tid,
                        const float* __restrict__ wout, const float* __restrict__ bout,
                        float* __restrict__ out, unsigned ep)
{
    constexpr int NKS = HH / 32;   // 16
    constexpr int NBB = NKS * 2;   // 32
    const int lane = tid & 63, lo = lane & 15, hi = lane >> 4;
    const int w = tid >> 6, og = w >> 1, ctbase = (w & 1) * 2;
    const int obase = (lwg * 2 + og) * 16;

    bf16x8 aF[NKS];
    #pragma unroll
    for (int ks = 0; ks < NKS; ++ks) {
        const float4* p = (const float4*)(wout + (size_t)(obase + lo) * HH + ks * 32 + hi * 8);
        aF[ks] = pack8(p[0], p[1]);
    }
    f32x4 biasv;
    #pragma unroll
    for (int r = 0; r < 4; ++r) biasv[r] = bout[obase + hi * 4 + r];

    for (int s = 0; s <= TT + 1; ++s) {
        const int t = s - 2;
        if (t >= 0 && t < TT) {
            const bf16x8* src = g_h2f[t & 1];
            bf16x8 bb[NBB];
            #pragma unroll
            for (int ks = 0; ks < NKS; ++ks)
                #pragma unroll
                for (int c = 0; c < 2; ++c)
                    bb[ks * 2 + c] = src[(ks * 4 + ctbase + c) * 64 + lane];
            __builtin_amdgcn_sched_barrier(0);

            f32x4 acc[2] = {biasv, biasv};
            #pragma unroll
            for (int ks = 0; ks < NKS; ++ks)
                #pragma unroll
                for (int c = 0; c < 2; ++c)
                    acc[c] = __builtin_amdgcn_mfma_f32_16x16x32_bf16(
                        aF[ks], bb[ks * 2 + c], acc[c], 0, 0, 0);
            #pragma unroll
            for (int c = 0; c < 2; ++c)
                #pragma unroll
                for (int r = 0; r < 4; ++r) {
                    const int b = (ctbase + c) * 16 + lo, o = obase + hi * 4 + r;
                    out[(size_t)t * BB * DOUT + (size_t)b * DOUT + o] = acc[c][r];
                }
        }
        gridbar(++ep, wg, tid);
    }
}

extern "C" __global__ void __launch_bounds__(256, 1)
lstm2_fused(const float* __restrict__ x,
            const float* __restrict__ wih0, const float* __restrict__ whh0,
            const float* __restrict__ bih0, const float* __restrict__ bhh0,
            const float* __restrict__ wih1, const float* __restrict__ whh1,
            const float* __restrict__ bih1, const float* __restrict__ bhh1,
            const float* __restrict__ wout, const float* __restrict__ bout,
            float* __restrict__ out)
{
    const int tid = threadIdx.x, wg = blockIdx.x;

    const unsigned base = __hip_atomic_load(&g_epoch_base, __ATOMIC_RELAXED,
                                            __HIP_MEMORY_SCOPE_AGENT);
    unsigned ep = base;

    // zero t=-1 parity ring buffers (h1f[1], h2f[1]) as uint4 lines
    {
        const int gidx = wg * 256 + tid;
        if (gidx < 4096) {
            ((uint4*)g_h1f[1])[gidx] = uint4{0, 0, 0, 0};
            ((uint4*)g_h2f[1])[gidx] = uint4{0, 0, 0, 0};
        }
    }
    gridbar(++ep, wg, tid);

    if (wg < NWG_L0)
        run_layer<0, 2>(wg, wg, tid, wih0, whh0, bih0, bhh0, out, ep);
    else if (wg < NWG_L0 + NWG_L1)
        run_layer<1, 1>(wg - NWG_L0, wg, tid, wih1, whh1, bih1, bhh1, out, ep);
    else
        run_out(wg - NWG_L0 - NWG_L1, wg, tid, wout, bout, out, ep);

    if (wg == 0 && tid == 0)
        __hip_atomic_store(&g_epoch_base, base + NBARRIERS, __ATOMIC_RELAXED,
                           __HIP_MEMORY_SCOPE_AGENT);
}

extern "C" void kernel_launch(void* const* d_in, const int* in_sizes, int n_in,
                              void* d_out, int out_size, void* d_ws, size_t ws_size,
                              hipStream_t stream) {
    const float* x    = (const float*)d_in[0];
    const float* wih0 = (const float*)d_in[1];
    const float* whh0 = (const float*)d_in[2];
    const float* bih0 = (const float*)d_in[3];
    const float* bhh0 = (const float*)d_in[4];
    const float* wih1 = (const float*)d_in[5];
    const float* whh1 = (const float*)d_in[6];
    const float* bih1 = (const float*)d_in[7];
    const float* bhh1 = (const float*)d_in[8];
    const float* wout = (const float*)d_in[9];
    const float* bout = (const float*)d_in[10];
    float* out = (float*)d_out;

    hipLaunchKernelGGL(pack_x, dim3(TT), dim3(256), 0, stream, x);
    hipLaunchKernelGGL(lstm2_fused, dim3(NWG_TOT), dim3(256), 0, stream,
                       x, wih0, whh0, bih0, bhh0, wih1, whh1, bih1, bhh1,
                       wout, bout, out);
}